// Round 2
// baseline (982.633 us; speedup 1.0000x reference)
//
#include <hip/hip_runtime.h>
#include <hip/hip_bf16.h>

// GraphSAGE link predictor:
//   h = relu( mean_agg(x)@w1l.T + b1 + x@w1r.T )
//   z = mean_agg(h)@w2l.T + b2 + h@w2r.T
//   out[e] = dot(z[src[e]], z[dst[e]])
//
// Strategy: linearity lets us compute xl = x@w1l.T FIRST, then mean-aggregate
// xl (and similarly hl for layer 2, which is only 64 wide). Aggregation is done
// gather-style via a CSR (grouped by dst) built per-call in the workspace —
// avoids ~310M float atomics.
//
// NOTE: harness passes integer inputs as int32 (edge_index buffer is 2*E int32),
// NOT int64 — reading as long long page-faulted in R1.

#define N_NODES   100000
#define E_EDGES   1600000
#define IN_C      128
#define HID_C     128
#define OUT_C     64

// ---------------------------------------------------------------- CSR build
__global__ __launch_bounds__(256) void count_deg(const int* __restrict__ ei,
                                                 int* __restrict__ cnt, int E, int n) {
    int e = blockIdx.x * 256 + threadIdx.x;
    if (e >= E) return;
    int d = ei[(size_t)E + e];
    if ((unsigned)d < (unsigned)n) atomicAdd(&cnt[d], 1);
}

__global__ __launch_bounds__(256) void scan_partial(const int* __restrict__ cnt,
                                                    int* __restrict__ tile_sums, int n) {
    __shared__ int sd[256];
    int t = threadIdx.x;
    int base = blockIdx.x * 1024;
    int s = 0;
#pragma unroll
    for (int i = 0; i < 4; ++i) {
        int idx = base + t * 4 + i;
        if (idx < n) s += cnt[idx];
    }
    sd[t] = s;
    __syncthreads();
    for (int o = 128; o > 0; o >>= 1) {
        if (t < o) sd[t] += sd[t + o];
        __syncthreads();
    }
    if (t == 0) tile_sums[blockIdx.x] = sd[0];
}

__global__ __launch_bounds__(256) void scan_tiles(int* __restrict__ tile_sums, int nt) {
    __shared__ int sd[256];
    int t = threadIdx.x;
    int v = (t < nt) ? tile_sums[t] : 0;
    sd[t] = v;
    __syncthreads();
    for (int o = 1; o < 256; o <<= 1) {
        int vv = 0;
        if (t >= o) vv = sd[t - o];
        __syncthreads();
        sd[t] += vv;
        __syncthreads();
    }
    if (t < nt) tile_sums[t] = sd[t] - v;   // exclusive
}

__global__ __launch_bounds__(256) void scan_final(const int* __restrict__ cnt,
                                                  const int* __restrict__ tile_sums,
                                                  int* __restrict__ row_ptr,
                                                  int* __restrict__ cursor,
                                                  float* __restrict__ inv_deg,
                                                  int n, int E) {
    __shared__ int sd[256];
    int t = threadIdx.x;
    int base = blockIdx.x * 1024;
    int loc[4];
    int s = 0;
#pragma unroll
    for (int i = 0; i < 4; ++i) {
        int idx = base + t * 4 + i;
        loc[i] = (idx < n) ? cnt[idx] : 0;
        s += loc[i];
    }
    int own = s;
    sd[t] = s;
    __syncthreads();
    for (int o = 1; o < 256; o <<= 1) {
        int vv = 0;
        if (t >= o) vv = sd[t - o];
        __syncthreads();
        sd[t] += vv;
        __syncthreads();
    }
    int off = tile_sums[blockIdx.x] + sd[t] - own;
#pragma unroll
    for (int i = 0; i < 4; ++i) {
        int idx = base + t * 4 + i;
        if (idx < n) {
            row_ptr[idx] = off;
            cursor[idx]  = off;
            inv_deg[idx] = 1.0f / (float)max(loc[i], 1);
            off += loc[i];
        }
    }
    if (blockIdx.x == 0 && t == 0) row_ptr[n] = E;
}

__global__ __launch_bounds__(256) void fill_csr(const int* __restrict__ ei,
                                                int* __restrict__ cursor,
                                                int* __restrict__ csr_src, int E, int n) {
    int e = blockIdx.x * 256 + threadIdx.x;
    if (e >= E) return;
    int d = ei[(size_t)E + e];
    int s = ei[e];
    if ((unsigned)d < (unsigned)n && (unsigned)s < (unsigned)n) {
        int pos = atomicAdd(&cursor[d], 1);
        csr_src[pos] = s;
    }
}

// ---------------------------------------------------------------- fused dual GEMM
// outA[n][c] = sum_k in[n][k]*wA[c][k];  outB[n][c] = sum_k in[n][k]*wB[c][k] + bias[c]
template <int K, int COLS>
__global__ __launch_bounds__(256) void gemm_dual(const float* __restrict__ in,
                                                 const float* __restrict__ wA,
                                                 const float* __restrict__ wB,
                                                 const float* __restrict__ bias,
                                                 float* __restrict__ outA,
                                                 float* __restrict__ outB, int nrows) {
    constexpr int TM  = 32;
    constexpr int CPT = (2 * COLS) / 64;     // cols per thread (4 for 128, 2 for 64)
    __shared__ float xs[TM][K];              // 16 KB

    int t    = threadIdx.x;
    int row0 = blockIdx.x * TM;

    // cooperative x-tile load (coalesced float4)
    for (int i = t; i < TM * K / 4; i += 256) {
        int r  = i / (K / 4);
        int cc = i % (K / 4);
        int gr = row0 + r;
        float4 v = make_float4(0.f, 0.f, 0.f, 0.f);
        if (gr < nrows) v = ((const float4*)(in + (size_t)gr * K))[cc];
        ((float4*)&xs[r][0])[cc] = v;
    }
    __syncthreads();

    int lane = t & 63;
    int r0   = (t >> 6) * 8;                 // 8 rows per thread

    const float* wp[CPT];
#pragma unroll
    for (int j = 0; j < CPT; ++j) {
        int c = lane + j * 64;
        wp[j] = (c < COLS) ? (wA + (size_t)c * K) : (wB + (size_t)(c - COLS) * K);
    }

    float acc[8][CPT];
#pragma unroll
    for (int i = 0; i < 8; ++i)
#pragma unroll
        for (int j = 0; j < CPT; ++j) acc[i][j] = 0.f;

    for (int k = 0; k < K; k += 4) {
        float4 w[CPT];
#pragma unroll
        for (int j = 0; j < CPT; ++j) w[j] = *(const float4*)(wp[j] + k);
#pragma unroll
        for (int i = 0; i < 8; ++i) {
            float4 xv = *(const float4*)&xs[r0 + i][k];   // broadcast within row-group
#pragma unroll
            for (int j = 0; j < CPT; ++j) {
                acc[i][j] = fmaf(xv.x, w[j].x, acc[i][j]);
                acc[i][j] = fmaf(xv.y, w[j].y, acc[i][j]);
                acc[i][j] = fmaf(xv.z, w[j].z, acc[i][j]);
                acc[i][j] = fmaf(xv.w, w[j].w, acc[i][j]);
            }
        }
    }

#pragma unroll
    for (int i = 0; i < 8; ++i) {
        int gr = row0 + r0 + i;
        if (gr >= nrows) continue;
#pragma unroll
        for (int j = 0; j < CPT; ++j) {
            int c = lane + j * 64;
            if (c < COLS) outA[(size_t)gr * COLS + c] = acc[i][j];
            else          outB[(size_t)gr * COLS + (c - COLS)] = acc[i][j] + bias[c - COLS];
        }
    }
}

// ---------------------------------------------------------------- aggregate + combine
// out[n] = relu?( (sum_{s in csr[n]} gl[s]) * inv_deg[n] + other[n] ) ; width C floats
template <int C>
__global__ __launch_bounds__(256) void agg_combine(const float* __restrict__ gl,
                                                   const float* __restrict__ other,
                                                   const int* __restrict__ row_ptr,
                                                   const int* __restrict__ csr_src,
                                                   const float* __restrict__ inv_deg,
                                                   float* __restrict__ outp,
                                                   int n, int do_relu) {
    constexpr int G = C / 4;                 // lanes per node
    int t = threadIdx.x;
    int g = t / G, l = t % G;
    int node = blockIdx.x * (256 / G) + g;
    if (node >= n) return;

    int p0 = row_ptr[node], p1 = row_ptr[node + 1];
    float ax = 0.f, ay = 0.f, az = 0.f, aw = 0.f;
    for (int p = p0; p < p1; ++p) {
        int s = csr_src[p];
        float4 v = ((const float4*)(gl + (size_t)s * C))[l];
        ax += v.x; ay += v.y; az += v.z; aw += v.w;
    }
    float id = inv_deg[node];
    float4 o = ((const float4*)(other + (size_t)node * C))[l];
    float4 r;
    r.x = fmaf(ax, id, o.x);
    r.y = fmaf(ay, id, o.y);
    r.z = fmaf(az, id, o.z);
    r.w = fmaf(aw, id, o.w);
    if (do_relu) {
        r.x = fmaxf(r.x, 0.f); r.y = fmaxf(r.y, 0.f);
        r.z = fmaxf(r.z, 0.f); r.w = fmaxf(r.w, 0.f);
    }
    ((float4*)(outp + (size_t)node * C))[l] = r;
}

// ---------------------------------------------------------------- decode
__global__ __launch_bounds__(256) void decode(const float* __restrict__ z,
                                              const int* __restrict__ ei,
                                              float* __restrict__ out, int E, int n) {
    int t = blockIdx.x * 256 + threadIdx.x;
    int e = t >> 4, l = t & 15;
    if (e >= E) return;
    int s = ei[e];
    int d = ei[(size_t)E + e];
    float p = 0.f;
    if ((unsigned)s < (unsigned)n && (unsigned)d < (unsigned)n) {
        float4 a = ((const float4*)(z + (size_t)s * OUT_C))[l];
        float4 b = ((const float4*)(z + (size_t)d * OUT_C))[l];
        p = a.x * b.x + a.y * b.y + a.z * b.z + a.w * b.w;
    }
    p += __shfl_xor(p, 8);
    p += __shfl_xor(p, 4);
    p += __shfl_xor(p, 2);
    p += __shfl_xor(p, 1);
    if (l == 0) out[e] = p;
}

// ---------------------------------------------------------------- launch
extern "C" void kernel_launch(void* const* d_in, const int* in_sizes, int n_in,
                              void* d_out, int out_size, void* d_ws, size_t ws_size,
                              hipStream_t stream) {
    const float* x   = (const float*)d_in[0];
    const int*   ei  = (const int*)d_in[1];
    const float* w1l = (const float*)d_in[2];
    const float* w1r = (const float*)d_in[3];
    const float* b1  = (const float*)d_in[4];
    const float* w2l = (const float*)d_in[5];
    const float* w2r = (const float*)d_in[6];
    const float* b2  = (const float*)d_in[7];
    float*       out = (float*)d_out;

    const int N = in_sizes[0] / IN_C;
    const int E = in_sizes[1] / 2;

    auto alignup = [](size_t v) { return (v + 255) & ~(size_t)255; };
    char* p = (char*)d_ws;
    int*   cnt       = (int*)p;   p += alignup((size_t)N * 4);
    int*   row_ptr   = (int*)p;   p += alignup((size_t)(N + 1) * 4);
    int*   cursor    = (int*)p;   p += alignup((size_t)N * 4);
    int*   tile_sums = (int*)p;   p += alignup((size_t)256 * 4);
    float* inv_deg   = (float*)p; p += alignup((size_t)N * 4);
    int*   csr_src   = (int*)p;   p += alignup((size_t)E * 4);
    float* A         = (float*)p; p += alignup((size_t)N * HID_C * 4);   // xl -> hl|hr
    float* B         = (float*)p; p += alignup((size_t)N * HID_C * 4);   // xr -> h (in place)

    const int nt = (N + 1023) / 1024;        // scan tiles

    // CSR build
    hipMemsetAsync(cnt, 0, (size_t)N * 4, stream);
    count_deg<<<(E + 255) / 256, 256, 0, stream>>>(ei, cnt, E, N);
    scan_partial<<<nt, 256, 0, stream>>>(cnt, tile_sums, N);
    scan_tiles<<<1, 256, 0, stream>>>(tile_sums, nt);
    scan_final<<<nt, 256, 0, stream>>>(cnt, tile_sums, row_ptr, cursor, inv_deg, N, E);
    fill_csr<<<(E + 255) / 256, 256, 0, stream>>>(ei, cursor, csr_src, E, N);

    // Layer 1: xl = x@w1l.T (A) ; xr = x@w1r.T + b1 (B)
    gemm_dual<IN_C, HID_C><<<(N + 31) / 32, 256, 0, stream>>>(x, w1l, w1r, b1, A, B, N);
    // h = relu(agg(xl)/deg + xr)  -> in place into B
    agg_combine<HID_C><<<(N + 7) / 8, 256, 0, stream>>>(A, B, row_ptr, csr_src, inv_deg, B, N, 1);

    // Layer 2: hl = h@w2l.T ; hr = h@w2r.T + b2  (both halves of A)
    float* hl = A;
    float* hr = A + (size_t)N * OUT_C;
    gemm_dual<HID_C, OUT_C><<<(N + 31) / 32, 256, 0, stream>>>(B, w2l, w2r, b2, hl, hr, N);
    // z = agg(hl)/deg + hr -> in place into hr
    agg_combine<OUT_C><<<(N + 15) / 16, 256, 0, stream>>>(hl, hr, row_ptr, csr_src, inv_deg, hr, N, 0);

    // decode
    decode<<<((size_t)E * 16 + 255) / 256, 256, 0, stream>>>(hr, ei, out, E, N);
}

// Round 3
// 793.780 us; speedup vs baseline: 1.2379x; 1.2379x over previous
//
#include <hip/hip_runtime.h>
#include <hip/hip_bf16.h>

// GraphSAGE link predictor:
//   h = relu( mean_agg(x)@w1l.T + b1 + x@w1r.T )
//   z = mean_agg(h)@w2l.T + b2 + h@w2r.T
//   out[e] = dot(z[src[e]], z[dst[e]])
//
// R3: replaced dot-product-style gemm_dual (lane=col -> 64-line divergent
// weight loads, VALUBusy 24%) with classic LDS-tiled SGEMM (128x128 tile,
// BK=32, 8x8 microtile). Both operands staged coalesced, read via b128 with
// lane broadcast.
//
// edge_index arrives as int32 (harness converts int64 inputs).

#define IN_C      128
#define HID_C     128
#define OUT_C     64

// ---------------------------------------------------------------- CSR build
__global__ __launch_bounds__(256) void count_deg(const int* __restrict__ ei,
                                                 int* __restrict__ cnt, int E, int n) {
    int e = blockIdx.x * 256 + threadIdx.x;
    if (e >= E) return;
    int d = ei[(size_t)E + e];
    if ((unsigned)d < (unsigned)n) atomicAdd(&cnt[d], 1);
}

__global__ __launch_bounds__(256) void scan_partial(const int* __restrict__ cnt,
                                                    int* __restrict__ tile_sums, int n) {
    __shared__ int sd[256];
    int t = threadIdx.x;
    int base = blockIdx.x * 1024;
    int s = 0;
#pragma unroll
    for (int i = 0; i < 4; ++i) {
        int idx = base + t * 4 + i;
        if (idx < n) s += cnt[idx];
    }
    sd[t] = s;
    __syncthreads();
    for (int o = 128; o > 0; o >>= 1) {
        if (t < o) sd[t] += sd[t + o];
        __syncthreads();
    }
    if (t == 0) tile_sums[blockIdx.x] = sd[0];
}

__global__ __launch_bounds__(256) void scan_tiles(int* __restrict__ tile_sums, int nt) {
    __shared__ int sd[256];
    int t = threadIdx.x;
    int v = (t < nt) ? tile_sums[t] : 0;
    sd[t] = v;
    __syncthreads();
    for (int o = 1; o < 256; o <<= 1) {
        int vv = 0;
        if (t >= o) vv = sd[t - o];
        __syncthreads();
        sd[t] += vv;
        __syncthreads();
    }
    if (t < nt) tile_sums[t] = sd[t] - v;   // exclusive
}

__global__ __launch_bounds__(256) void scan_final(const int* __restrict__ cnt,
                                                  const int* __restrict__ tile_sums,
                                                  int* __restrict__ row_ptr,
                                                  int* __restrict__ cursor,
                                                  float* __restrict__ inv_deg,
                                                  int n, int E) {
    __shared__ int sd[256];
    int t = threadIdx.x;
    int base = blockIdx.x * 1024;
    int loc[4];
    int s = 0;
#pragma unroll
    for (int i = 0; i < 4; ++i) {
        int idx = base + t * 4 + i;
        loc[i] = (idx < n) ? cnt[idx] : 0;
        s += loc[i];
    }
    int own = s;
    sd[t] = s;
    __syncthreads();
    for (int o = 1; o < 256; o <<= 1) {
        int vv = 0;
        if (t >= o) vv = sd[t - o];
        __syncthreads();
        sd[t] += vv;
        __syncthreads();
    }
    int off = tile_sums[blockIdx.x] + sd[t] - own;
#pragma unroll
    for (int i = 0; i < 4; ++i) {
        int idx = base + t * 4 + i;
        if (idx < n) {
            row_ptr[idx] = off;
            cursor[idx]  = off;
            inv_deg[idx] = 1.0f / (float)max(loc[i], 1);
            off += loc[i];
        }
    }
    if (blockIdx.x == 0 && t == 0) row_ptr[n] = E;
}

__global__ __launch_bounds__(256) void fill_csr(const int* __restrict__ ei,
                                                int* __restrict__ cursor,
                                                int* __restrict__ csr_src, int E, int n) {
    int e = blockIdx.x * 256 + threadIdx.x;
    if (e >= E) return;
    int d = ei[(size_t)E + e];
    int s = ei[e];
    if ((unsigned)d < (unsigned)n && (unsigned)s < (unsigned)n) {
        int pos = atomicAdd(&cursor[d], 1);
        csr_src[pos] = s;
    }
}

// ---------------------------------------------------------------- tiled dual GEMM
// Computes [outA | outB] = in @ [wA | wB].T, outB gets +bias.
// wA, wB are [COLS][K] row-major. Block tile: 128 rows x 128 cols.
// Grid: (ceil(nrows/128), 2*COLS/128).
template <int K, int COLS>
__global__ __launch_bounds__(256) void gemm_tile(const float* __restrict__ in,
                                                 const float* __restrict__ wA,
                                                 const float* __restrict__ wB,
                                                 const float* __restrict__ bias,
                                                 float* __restrict__ outA,
                                                 float* __restrict__ outB, int nrows) {
    constexpr int BK  = 32;
    constexpr int LDS_STRIDE = 132;          // 132 dwords = 528 B: 16B-aligned rows, bank-spread
    __shared__ float xs[BK][LDS_STRIDE];     // [k][row]
    __shared__ float ws[BK][LDS_STRIDE];     // [k][col]

    const int t  = threadIdx.x;
    const int tx = t & 15;                   // col group
    const int ty = t >> 4;                   // row group
    const int row0 = blockIdx.x * 128;
    const int col0 = blockIdx.y * 128;
    const int r0 = 4 * ty;                   // rows r0..r0+3 and 64+r0..64+r0+3
    const int c0 = 4 * tx;                   // cols c0..c0+3 and 64+c0..64+c0+3

    float acc[8][8];
#pragma unroll
    for (int i = 0; i < 8; ++i)
#pragma unroll
        for (int j = 0; j < 8; ++j) acc[i][j] = 0.f;

    for (int k0 = 0; k0 < K; k0 += BK) {
        // stage x tile: 128 rows x BK, transposed into xs[k][row]
#pragma unroll
        for (int j = 0; j < 4; ++j) {
            int idx = t + j * 256;           // 0..1023
            int r   = idx >> 3;              // 0..127
            int kq  = idx & 7;               // float4 index within BK
            int gr  = row0 + r;
            float4 v = make_float4(0.f, 0.f, 0.f, 0.f);
            if (gr < nrows) v = ((const float4*)(in + (size_t)gr * K))[(k0 >> 2) + kq];
            xs[4 * kq + 0][r] = v.x;
            xs[4 * kq + 1][r] = v.y;
            xs[4 * kq + 2][r] = v.z;
            xs[4 * kq + 3][r] = v.w;
        }
        // stage w tile: 128 block-cols x BK, transposed into ws[k][col]
#pragma unroll
        for (int j = 0; j < 4; ++j) {
            int idx = t + j * 256;
            int c   = idx >> 3;
            int kq  = idx & 7;
            int gc  = col0 + c;
            const float* wrow = (gc < COLS) ? (wA + (size_t)gc * K)
                                            : (wB + (size_t)(gc - COLS) * K);
            float4 v = ((const float4*)wrow)[(k0 >> 2) + kq];
            ws[4 * kq + 0][c] = v.x;
            ws[4 * kq + 1][c] = v.y;
            ws[4 * kq + 2][c] = v.z;
            ws[4 * kq + 3][c] = v.w;
        }
        __syncthreads();

#pragma unroll
        for (int k = 0; k < BK; ++k) {
            float4 xa = *(const float4*)&xs[k][r0];
            float4 xb = *(const float4*)&xs[k][64 + r0];
            float4 wa = *(const float4*)&ws[k][c0];
            float4 wb = *(const float4*)&ws[k][64 + c0];
            const float xv[8] = {xa.x, xa.y, xa.z, xa.w, xb.x, xb.y, xb.z, xb.w};
            const float wv[8] = {wa.x, wa.y, wa.z, wa.w, wb.x, wb.y, wb.z, wb.w};
#pragma unroll
            for (int i = 0; i < 8; ++i)
#pragma unroll
                for (int j = 0; j < 8; ++j)
                    acc[i][j] = fmaf(xv[i], wv[j], acc[i][j]);
        }
        __syncthreads();
    }

    // epilogue: write two float4 column segments per row; B-half gets bias
#pragma unroll
    for (int i = 0; i < 8; ++i) {
        int lr = (i < 4) ? (r0 + i) : (64 + r0 + i - 4);
        int gr = row0 + lr;
        if (gr >= nrows) continue;
#pragma unroll
        for (int half = 0; half < 2; ++half) {
            int lc = half * 64 + c0;
            int gc = col0 + lc;
            float4 v = make_float4(acc[i][half * 4 + 0], acc[i][half * 4 + 1],
                                   acc[i][half * 4 + 2], acc[i][half * 4 + 3]);
            if (gc < COLS) {
                ((float4*)(outA + (size_t)gr * COLS + gc))[0] = v;
            } else {
                int bc = gc - COLS;
                float4 bv = *(const float4*)(bias + bc);
                v.x += bv.x; v.y += bv.y; v.z += bv.z; v.w += bv.w;
                ((float4*)(outB + (size_t)gr * COLS + bc))[0] = v;
            }
        }
    }
}

// ---------------------------------------------------------------- aggregate + combine
// out[n] = relu?( (sum_{s in csr[n]} gl[s]) * inv_deg[n] + other[n] ) ; width C floats
template <int C>
__global__ __launch_bounds__(256) void agg_combine(const float* __restrict__ gl,
                                                   const float* __restrict__ other,
                                                   const int* __restrict__ row_ptr,
                                                   const int* __restrict__ csr_src,
                                                   const float* __restrict__ inv_deg,
                                                   float* __restrict__ outp,
                                                   int n, int do_relu) {
    constexpr int G = C / 4;                 // lanes per node
    int t = threadIdx.x;
    int g = t / G, l = t % G;
    int node = blockIdx.x * (256 / G) + g;
    if (node >= n) return;

    int p0 = row_ptr[node], p1 = row_ptr[node + 1];
    float ax = 0.f, ay = 0.f, az = 0.f, aw = 0.f;
    for (int p = p0; p < p1; ++p) {
        int s = csr_src[p];
        float4 v = ((const float4*)(gl + (size_t)s * C))[l];
        ax += v.x; ay += v.y; az += v.z; aw += v.w;
    }
    float id = inv_deg[node];
    float4 o = ((const float4*)(other + (size_t)node * C))[l];
    float4 r;
    r.x = fmaf(ax, id, o.x);
    r.y = fmaf(ay, id, o.y);
    r.z = fmaf(az, id, o.z);
    r.w = fmaf(aw, id, o.w);
    if (do_relu) {
        r.x = fmaxf(r.x, 0.f); r.y = fmaxf(r.y, 0.f);
        r.z = fmaxf(r.z, 0.f); r.w = fmaxf(r.w, 0.f);
    }
    ((float4*)(outp + (size_t)node * C))[l] = r;
}

// ---------------------------------------------------------------- decode
__global__ __launch_bounds__(256) void decode(const float* __restrict__ z,
                                              const int* __restrict__ ei,
                                              float* __restrict__ out, int E, int n) {
    int t = blockIdx.x * 256 + threadIdx.x;
    int e = t >> 4, l = t & 15;
    if (e >= E) return;
    int s = ei[e];
    int d = ei[(size_t)E + e];
    float p = 0.f;
    if ((unsigned)s < (unsigned)n && (unsigned)d < (unsigned)n) {
        float4 a = ((const float4*)(z + (size_t)s * OUT_C))[l];
        float4 b = ((const float4*)(z + (size_t)d * OUT_C))[l];
        p = a.x * b.x + a.y * b.y + a.z * b.z + a.w * b.w;
    }
    p += __shfl_xor(p, 8);
    p += __shfl_xor(p, 4);
    p += __shfl_xor(p, 2);
    p += __shfl_xor(p, 1);
    if (l == 0) out[e] = p;
}

// ---------------------------------------------------------------- launch
extern "C" void kernel_launch(void* const* d_in, const int* in_sizes, int n_in,
                              void* d_out, int out_size, void* d_ws, size_t ws_size,
                              hipStream_t stream) {
    const float* x   = (const float*)d_in[0];
    const int*   ei  = (const int*)d_in[1];
    const float* w1l = (const float*)d_in[2];
    const float* w1r = (const float*)d_in[3];
    const float* b1  = (const float*)d_in[4];
    const float* w2l = (const float*)d_in[5];
    const float* w2r = (const float*)d_in[6];
    const float* b2  = (const float*)d_in[7];
    float*       out = (float*)d_out;

    const int N = in_sizes[0] / IN_C;
    const int E = in_sizes[1] / 2;

    auto alignup = [](size_t v) { return (v + 255) & ~(size_t)255; };
    char* p = (char*)d_ws;
    int*   cnt       = (int*)p;   p += alignup((size_t)N * 4);
    int*   row_ptr   = (int*)p;   p += alignup((size_t)(N + 1) * 4);
    int*   cursor    = (int*)p;   p += alignup((size_t)N * 4);
    int*   tile_sums = (int*)p;   p += alignup((size_t)256 * 4);
    float* inv_deg   = (float*)p; p += alignup((size_t)N * 4);
    int*   csr_src   = (int*)p;   p += alignup((size_t)E * 4);
    float* A         = (float*)p; p += alignup((size_t)N * HID_C * 4);   // xl -> hl|hr
    float* B         = (float*)p; p += alignup((size_t)N * HID_C * 4);   // xr -> h (in place)

    const int nt = (N + 1023) / 1024;        // scan tiles

    // CSR build
    hipMemsetAsync(cnt, 0, (size_t)N * 4, stream);
    count_deg<<<(E + 255) / 256, 256, 0, stream>>>(ei, cnt, E, N);
    scan_partial<<<nt, 256, 0, stream>>>(cnt, tile_sums, N);
    scan_tiles<<<1, 256, 0, stream>>>(tile_sums, nt);
    scan_final<<<nt, 256, 0, stream>>>(cnt, tile_sums, row_ptr, cursor, inv_deg, N, E);
    fill_csr<<<(E + 255) / 256, 256, 0, stream>>>(ei, cursor, csr_src, E, N);

    const int rb = (N + 127) / 128;          // row tiles

    // Layer 1: xl = x@w1l.T (A) ; xr = x@w1r.T + b1 (B)
    {
        dim3 grid(rb, (2 * HID_C) / 128);
        gemm_tile<IN_C, HID_C><<<grid, 256, 0, stream>>>(x, w1l, w1r, b1, A, B, N);
    }
    // h = relu(agg(xl)/deg + xr)  -> in place into B
    agg_combine<HID_C><<<(N + 7) / 8, 256, 0, stream>>>(A, B, row_ptr, csr_src, inv_deg, B, N, 1);

    // Layer 2: hl = h@w2l.T ; hr = h@w2r.T + b2  (both halves of A)
    float* hl = A;
    float* hr = A + (size_t)N * OUT_C;
    {
        dim3 grid(rb, (2 * OUT_C) / 128);
        gemm_tile<HID_C, OUT_C><<<grid, 256, 0, stream>>>(B, w2l, w2r, b2, hl, hr, N);
    }
    // z = agg(hl)/deg + hr -> in place into hr
    agg_combine<OUT_C><<<(N + 15) / 16, 256, 0, stream>>>(hl, hr, row_ptr, csr_src, inv_deg, hr, N, 0);

    // decode
    decode<<<((size_t)E * 16 + 255) / 256, 256, 0, stream>>>(hr, ei, out, E, N);
}

// Round 4
// 738.469 us; speedup vs baseline: 1.3306x; 1.0749x over previous
//
#include <hip/hip_runtime.h>
#include <hip/hip_bf16.h>

// GraphSAGE link predictor:
//   h = relu( mean_agg(x)@w1l.T + b1 + x@w1r.T )
//   z = mean_agg(h)@w2l.T + b2 + h@w2r.T
//   out[e] = dot(z[src[e]], z[dst[e]])
//
// R3: LDS-tiled SGEMM (128x128, BK=32, 8x8 microtile) — fixed VALUBusy 24% GEMM.
// R4: XCD-partitioned CSR build. R3 counters: fill_csr WRITE_SIZE=105MB for a
//     6.4MB payload (1.6M scattered 4B stores x 64B lines, dirtied from all 8
//     non-coherent XCD L2s -> every partial line spills to HBM). Partition dst
//     space into 8 ranges, block b handles range b&7 (round-robin block->XCD
//     dispatch => each csr/cnt line owned by ONE XCD's L2). Trades 8x coalesced
//     L3-resident edge reads for ~200MB of random HBM writes.
//
// edge_index arrives as int32 (harness converts int64 inputs).

#define IN_C      128
#define HID_C     128
#define OUT_C     64
#define NPART     8
#define SLICE_E   4096   // edges per block slice in partitioned kernels

// ---------------------------------------------------------------- CSR build
__global__ __launch_bounds__(256) void count_deg(const int* __restrict__ ei,
                                                 int* __restrict__ cnt, int E, int n) {
    const int range = blockIdx.x & (NPART - 1);
    const int slice = blockIdx.x >> 3;
    const int nr = (n + NPART - 1) / NPART;
    const int lo = range * nr;
    const int hi = min(n, lo + nr);
    const int e1 = min(E, (slice + 1) * SLICE_E);
    for (int e = slice * SLICE_E + threadIdx.x; e < e1; e += 256) {
        int d = ei[(size_t)E + e];
        if (d >= lo && d < hi) atomicAdd(&cnt[d], 1);
    }
}

__global__ __launch_bounds__(256) void scan_partial(const int* __restrict__ cnt,
                                                    int* __restrict__ tile_sums, int n) {
    __shared__ int sd[256];
    int t = threadIdx.x;
    int base = blockIdx.x * 1024;
    int s = 0;
#pragma unroll
    for (int i = 0; i < 4; ++i) {
        int idx = base + t * 4 + i;
        if (idx < n) s += cnt[idx];
    }
    sd[t] = s;
    __syncthreads();
    for (int o = 128; o > 0; o >>= 1) {
        if (t < o) sd[t] += sd[t + o];
        __syncthreads();
    }
    if (t == 0) tile_sums[blockIdx.x] = sd[0];
}

__global__ __launch_bounds__(256) void scan_tiles(int* __restrict__ tile_sums, int nt) {
    __shared__ int sd[256];
    int t = threadIdx.x;
    int v = (t < nt) ? tile_sums[t] : 0;
    sd[t] = v;
    __syncthreads();
    for (int o = 1; o < 256; o <<= 1) {
        int vv = 0;
        if (t >= o) vv = sd[t - o];
        __syncthreads();
        sd[t] += vv;
        __syncthreads();
    }
    if (t < nt) tile_sums[t] = sd[t] - v;   // exclusive
}

__global__ __launch_bounds__(256) void scan_final(const int* __restrict__ cnt,
                                                  const int* __restrict__ tile_sums,
                                                  int* __restrict__ row_ptr,
                                                  int* __restrict__ cursor,
                                                  float* __restrict__ inv_deg,
                                                  int n, int E) {
    __shared__ int sd[256];
    int t = threadIdx.x;
    int base = blockIdx.x * 1024;
    int loc[4];
    int s = 0;
#pragma unroll
    for (int i = 0; i < 4; ++i) {
        int idx = base + t * 4 + i;
        loc[i] = (idx < n) ? cnt[idx] : 0;
        s += loc[i];
    }
    int own = s;
    sd[t] = s;
    __syncthreads();
    for (int o = 1; o < 256; o <<= 1) {
        int vv = 0;
        if (t >= o) vv = sd[t - o];
        __syncthreads();
        sd[t] += vv;
        __syncthreads();
    }
    int off = tile_sums[blockIdx.x] + sd[t] - own;
#pragma unroll
    for (int i = 0; i < 4; ++i) {
        int idx = base + t * 4 + i;
        if (idx < n) {
            row_ptr[idx] = off;
            cursor[idx]  = off;
            inv_deg[idx] = 1.0f / (float)max(loc[i], 1);
            off += loc[i];
        }
    }
    if (blockIdx.x == 0 && t == 0) row_ptr[n] = E;
}

__global__ __launch_bounds__(256) void fill_csr(const int* __restrict__ ei,
                                                int* __restrict__ cursor,
                                                int* __restrict__ csr_src, int E, int n) {
    const int range = blockIdx.x & (NPART - 1);
    const int slice = blockIdx.x >> 3;
    const int nr = (n + NPART - 1) / NPART;
    const int lo = range * nr;
    const int hi = min(n, lo + nr);
    const int e1 = min(E, (slice + 1) * SLICE_E);
    for (int e = slice * SLICE_E + threadIdx.x; e < e1; e += 256) {
        int d = ei[(size_t)E + e];
        if (d >= lo && d < hi) {
            int s = ei[e];
            if ((unsigned)s < (unsigned)n) {
                int pos = atomicAdd(&cursor[d], 1);
                csr_src[pos] = s;
            }
        }
    }
}

// ---------------------------------------------------------------- tiled dual GEMM
// Computes [outA | outB] = in @ [wA | wB].T, outB gets +bias.
// wA, wB are [COLS][K] row-major. Block tile: 128 rows x 128 cols.
// Grid: (ceil(nrows/128), 2*COLS/128).
template <int K, int COLS>
__global__ __launch_bounds__(256) void gemm_tile(const float* __restrict__ in,
                                                 const float* __restrict__ wA,
                                                 const float* __restrict__ wB,
                                                 const float* __restrict__ bias,
                                                 float* __restrict__ outA,
                                                 float* __restrict__ outB, int nrows) {
    constexpr int BK  = 32;
    constexpr int LDS_STRIDE = 132;          // 132 dwords = 528 B: 16B-aligned rows, bank-spread
    __shared__ float xs[BK][LDS_STRIDE];     // [k][row]
    __shared__ float ws[BK][LDS_STRIDE];     // [k][col]

    const int t  = threadIdx.x;
    const int tx = t & 15;                   // col group
    const int ty = t >> 4;                   // row group
    const int row0 = blockIdx.x * 128;
    const int col0 = blockIdx.y * 128;
    const int r0 = 4 * ty;                   // rows r0..r0+3 and 64+r0..64+r0+3
    const int c0 = 4 * tx;                   // cols c0..c0+3 and 64+c0..64+c0+3

    float acc[8][8];
#pragma unroll
    for (int i = 0; i < 8; ++i)
#pragma unroll
        for (int j = 0; j < 8; ++j) acc[i][j] = 0.f;

    for (int k0 = 0; k0 < K; k0 += BK) {
        // stage x tile: 128 rows x BK, transposed into xs[k][row]
#pragma unroll
        for (int j = 0; j < 4; ++j) {
            int idx = t + j * 256;           // 0..1023
            int r   = idx >> 3;              // 0..127
            int kq  = idx & 7;               // float4 index within BK
            int gr  = row0 + r;
            float4 v = make_float4(0.f, 0.f, 0.f, 0.f);
            if (gr < nrows) v = ((const float4*)(in + (size_t)gr * K))[(k0 >> 2) + kq];
            xs[4 * kq + 0][r] = v.x;
            xs[4 * kq + 1][r] = v.y;
            xs[4 * kq + 2][r] = v.z;
            xs[4 * kq + 3][r] = v.w;
        }
        // stage w tile: 128 block-cols x BK, transposed into ws[k][col]
#pragma unroll
        for (int j = 0; j < 4; ++j) {
            int idx = t + j * 256;
            int c   = idx >> 3;
            int kq  = idx & 7;
            int gc  = col0 + c;
            const float* wrow = (gc < COLS) ? (wA + (size_t)gc * K)
                                            : (wB + (size_t)(gc - COLS) * K);
            float4 v = ((const float4*)wrow)[(k0 >> 2) + kq];
            ws[4 * kq + 0][c] = v.x;
            ws[4 * kq + 1][c] = v.y;
            ws[4 * kq + 2][c] = v.z;
            ws[4 * kq + 3][c] = v.w;
        }
        __syncthreads();

#pragma unroll
        for (int k = 0; k < BK; ++k) {
            float4 xa = *(const float4*)&xs[k][r0];
            float4 xb = *(const float4*)&xs[k][64 + r0];
            float4 wa = *(const float4*)&ws[k][c0];
            float4 wb = *(const float4*)&ws[k][64 + c0];
            const float xv[8] = {xa.x, xa.y, xa.z, xa.w, xb.x, xb.y, xb.z, xb.w};
            const float wv[8] = {wa.x, wa.y, wa.z, wa.w, wb.x, wb.y, wb.z, wb.w};
#pragma unroll
            for (int i = 0; i < 8; ++i)
#pragma unroll
                for (int j = 0; j < 8; ++j)
                    acc[i][j] = fmaf(xv[i], wv[j], acc[i][j]);
        }
        __syncthreads();
    }

    // epilogue: write two float4 column segments per row; B-half gets bias
#pragma unroll
    for (int i = 0; i < 8; ++i) {
        int lr = (i < 4) ? (r0 + i) : (64 + r0 + i - 4);
        int gr = row0 + lr;
        if (gr >= nrows) continue;
#pragma unroll
        for (int half = 0; half < 2; ++half) {
            int lc = half * 64 + c0;
            int gc = col0 + lc;
            float4 v = make_float4(acc[i][half * 4 + 0], acc[i][half * 4 + 1],
                                   acc[i][half * 4 + 2], acc[i][half * 4 + 3]);
            if (gc < COLS) {
                ((float4*)(outA + (size_t)gr * COLS + gc))[0] = v;
            } else {
                int bc = gc - COLS;
                float4 bv = *(const float4*)(bias + bc);
                v.x += bv.x; v.y += bv.y; v.z += bv.z; v.w += bv.w;
                ((float4*)(outB + (size_t)gr * COLS + bc))[0] = v;
            }
        }
    }
}

// ---------------------------------------------------------------- aggregate + combine
// out[n] = relu?( (sum_{s in csr[n]} gl[s]) * inv_deg[n] + other[n] ) ; width C floats
template <int C>
__global__ __launch_bounds__(256) void agg_combine(const float* __restrict__ gl,
                                                   const float* __restrict__ other,
                                                   const int* __restrict__ row_ptr,
                                                   const int* __restrict__ csr_src,
                                                   const float* __restrict__ inv_deg,
                                                   float* __restrict__ outp,
                                                   int n, int do_relu) {
    constexpr int G = C / 4;                 // lanes per node
    int t = threadIdx.x;
    int g = t / G, l = t % G;
    int node = blockIdx.x * (256 / G) + g;
    if (node >= n) return;

    int p0 = row_ptr[node], p1 = row_ptr[node + 1];
    float ax = 0.f, ay = 0.f, az = 0.f, aw = 0.f;
    for (int p = p0; p < p1; ++p) {
        int s = csr_src[p];
        float4 v = ((const float4*)(gl + (size_t)s * C))[l];
        ax += v.x; ay += v.y; az += v.z; aw += v.w;
    }
    float id = inv_deg[node];
    float4 o = ((const float4*)(other + (size_t)node * C))[l];
    float4 r;
    r.x = fmaf(ax, id, o.x);
    r.y = fmaf(ay, id, o.y);
    r.z = fmaf(az, id, o.z);
    r.w = fmaf(aw, id, o.w);
    if (do_relu) {
        r.x = fmaxf(r.x, 0.f); r.y = fmaxf(r.y, 0.f);
        r.z = fmaxf(r.z, 0.f); r.w = fmaxf(r.w, 0.f);
    }
    ((float4*)(outp + (size_t)node * C))[l] = r;
}

// ---------------------------------------------------------------- decode
__global__ __launch_bounds__(256) void decode(const float* __restrict__ z,
                                              const int* __restrict__ ei,
                                              float* __restrict__ out, int E, int n) {
    int t = blockIdx.x * 256 + threadIdx.x;
    int e = t >> 4, l = t & 15;
    if (e >= E) return;
    int s = ei[e];
    int d = ei[(size_t)E + e];
    float p = 0.f;
    if ((unsigned)s < (unsigned)n && (unsigned)d < (unsigned)n) {
        float4 a = ((const float4*)(z + (size_t)s * OUT_C))[l];
        float4 b = ((const float4*)(z + (size_t)d * OUT_C))[l];
        p = a.x * b.x + a.y * b.y + a.z * b.z + a.w * b.w;
    }
    p += __shfl_xor(p, 8);
    p += __shfl_xor(p, 4);
    p += __shfl_xor(p, 2);
    p += __shfl_xor(p, 1);
    if (l == 0) out[e] = p;
}

// ---------------------------------------------------------------- launch
extern "C" void kernel_launch(void* const* d_in, const int* in_sizes, int n_in,
                              void* d_out, int out_size, void* d_ws, size_t ws_size,
                              hipStream_t stream) {
    const float* x   = (const float*)d_in[0];
    const int*   ei  = (const int*)d_in[1];
    const float* w1l = (const float*)d_in[2];
    const float* w1r = (const float*)d_in[3];
    const float* b1  = (const float*)d_in[4];
    const float* w2l = (const float*)d_in[5];
    const float* w2r = (const float*)d_in[6];
    const float* b2  = (const float*)d_in[7];
    float*       out = (float*)d_out;

    const int N = in_sizes[0] / IN_C;
    const int E = in_sizes[1] / 2;

    auto alignup = [](size_t v) { return (v + 255) & ~(size_t)255; };
    char* p = (char*)d_ws;
    int*   cnt       = (int*)p;   p += alignup((size_t)N * 4);
    int*   row_ptr   = (int*)p;   p += alignup((size_t)(N + 1) * 4);
    int*   cursor    = (int*)p;   p += alignup((size_t)N * 4);
    int*   tile_sums = (int*)p;   p += alignup((size_t)256 * 4);
    float* inv_deg   = (float*)p; p += alignup((size_t)N * 4);
    int*   csr_src   = (int*)p;   p += alignup((size_t)E * 4);
    float* A         = (float*)p; p += alignup((size_t)N * HID_C * 4);   // xl -> hl|hr
    float* B         = (float*)p; p += alignup((size_t)N * HID_C * 4);   // xr -> h (in place)

    const int nt = (N + 1023) / 1024;                 // scan tiles
    const int nslice = (E + SLICE_E - 1) / SLICE_E;   // edge slices for partitioned kernels

    // CSR build (count/fill are XCD-partitioned: block b handles dst range b&7)
    hipMemsetAsync(cnt, 0, (size_t)N * 4, stream);
    count_deg<<<nslice * NPART, 256, 0, stream>>>(ei, cnt, E, N);
    scan_partial<<<nt, 256, 0, stream>>>(cnt, tile_sums, N);
    scan_tiles<<<1, 256, 0, stream>>>(tile_sums, nt);
    scan_final<<<nt, 256, 0, stream>>>(cnt, tile_sums, row_ptr, cursor, inv_deg, N, E);
    fill_csr<<<nslice * NPART, 256, 0, stream>>>(ei, cursor, csr_src, E, N);

    const int rb = (N + 127) / 128;          // row tiles

    // Layer 1: xl = x@w1l.T (A) ; xr = x@w1r.T + b1 (B)
    {
        dim3 grid(rb, (2 * HID_C) / 128);
        gemm_tile<IN_C, HID_C><<<grid, 256, 0, stream>>>(x, w1l, w1r, b1, A, B, N);
    }
    // h = relu(agg(xl)/deg + xr)  -> in place into B
    agg_combine<HID_C><<<(N + 7) / 8, 256, 0, stream>>>(A, B, row_ptr, csr_src, inv_deg, B, N, 1);

    // Layer 2: hl = h@w2l.T ; hr = h@w2r.T + b2  (both halves of A)
    float* hl = A;
    float* hr = A + (size_t)N * OUT_C;
    {
        dim3 grid(rb, (2 * OUT_C) / 128);
        gemm_tile<HID_C, OUT_C><<<grid, 256, 0, stream>>>(B, w2l, w2r, b2, hl, hr, N);
    }
    // z = agg(hl)/deg + hr -> in place into hr
    agg_combine<OUT_C><<<(N + 15) / 16, 256, 0, stream>>>(hl, hr, row_ptr, csr_src, inv_deg, hr, N, 0);

    // decode
    decode<<<((size_t)E * 16 + 255) / 256, 256, 0, stream>>>(hr, ei, out, E, N);
}

// Round 5
// 524.897 us; speedup vs baseline: 1.8721x; 1.4069x over previous
//
#include <hip/hip_runtime.h>

// GraphSAGE link predictor, bf16-MFMA edition.
//   h = relu( mean_agg(x)@w1l.T + b1 + x@w1r.T )
//   z = mean_agg(h)@w2l.T + b2 + h@w2r.T
//   out[e] = dot(z[src[e]], z[dst[e]])
//
// R3: LDS-tiled fp32 SGEMM. R4: XCD-partitioned CSR build (fill_csr 137->~30us).
// R5: R4 counters showed gemm_tile (134us) co-saturating LDS pipe + fp32 VALU
//     (1 B LDS per FMA; VALUBusy 56%). Moved GEMMs to bf16 MFMA
//     (16x16x32): A/B fragments are 8 contiguous k's from row-major bf16 -> no
//     transpose; weights LDS-resident (padded rows, conflict-free b128);
//     2 row-tiles/wave => 2 MFMA per B-frag read => MFMA-bound, HBM-write floor.
//     Intermediates xl/xr/h/hl/hr stored bf16 (halves agg gather traffic);
//     aggregation math + z + decode stay fp32.
//
// edge_index arrives as int32 (harness converts int64 inputs).

#define IN_C      128
#define HID_C     128
#define OUT_C     64
#define NPART     8
#define SLICE_E   4096

typedef unsigned short u16;
typedef __attribute__((ext_vector_type(8))) __bf16 bf16x8;
typedef __attribute__((ext_vector_type(4))) float f32x4;

__device__ inline u16 f2bf(float f) {                 // RNE f32 -> bf16
    unsigned u = __float_as_uint(f);
    u += 0x7fff + ((u >> 16) & 1);
    return (u16)(u >> 16);
}
__device__ inline float bflo(unsigned v) { return __uint_as_float(v << 16); }
__device__ inline float bfhi(unsigned v) { return __uint_as_float(v & 0xffff0000u); }

// ---------------------------------------------------------------- CSR build
__global__ __launch_bounds__(256) void count_deg(const int* __restrict__ ei,
                                                 int* __restrict__ cnt, int E, int n) {
    const int range = blockIdx.x & (NPART - 1);
    const int slice = blockIdx.x >> 3;
    const int nr = (n + NPART - 1) / NPART;
    const int lo = range * nr;
    const int hi = min(n, lo + nr);
    const int e1 = min(E, (slice + 1) * SLICE_E);
    for (int e = slice * SLICE_E + threadIdx.x; e < e1; e += 256) {
        int d = ei[(size_t)E + e];
        if (d >= lo && d < hi) atomicAdd(&cnt[d], 1);
    }
}

__global__ __launch_bounds__(256) void scan_partial(const int* __restrict__ cnt,
                                                    int* __restrict__ tile_sums, int n) {
    __shared__ int sd[256];
    int t = threadIdx.x;
    int base = blockIdx.x * 1024;
    int s = 0;
#pragma unroll
    for (int i = 0; i < 4; ++i) {
        int idx = base + t * 4 + i;
        if (idx < n) s += cnt[idx];
    }
    sd[t] = s;
    __syncthreads();
    for (int o = 128; o > 0; o >>= 1) {
        if (t < o) sd[t] += sd[t + o];
        __syncthreads();
    }
    if (t == 0) tile_sums[blockIdx.x] = sd[0];
}

__global__ __launch_bounds__(256) void scan_tiles(int* __restrict__ tile_sums, int nt) {
    __shared__ int sd[256];
    int t = threadIdx.x;
    int v = (t < nt) ? tile_sums[t] : 0;
    sd[t] = v;
    __syncthreads();
    for (int o = 1; o < 256; o <<= 1) {
        int vv = 0;
        if (t >= o) vv = sd[t - o];
        __syncthreads();
        sd[t] += vv;
        __syncthreads();
    }
    if (t < nt) tile_sums[t] = sd[t] - v;   // exclusive
}

__global__ __launch_bounds__(256) void scan_final(const int* __restrict__ cnt,
                                                  const int* __restrict__ tile_sums,
                                                  int* __restrict__ row_ptr,
                                                  int* __restrict__ cursor,
                                                  float* __restrict__ inv_deg,
                                                  int n, int E) {
    __shared__ int sd[256];
    int t = threadIdx.x;
    int base = blockIdx.x * 1024;
    int loc[4];
    int s = 0;
#pragma unroll
    for (int i = 0; i < 4; ++i) {
        int idx = base + t * 4 + i;
        loc[i] = (idx < n) ? cnt[idx] : 0;
        s += loc[i];
    }
    int own = s;
    sd[t] = s;
    __syncthreads();
    for (int o = 1; o < 256; o <<= 1) {
        int vv = 0;
        if (t >= o) vv = sd[t - o];
        __syncthreads();
        sd[t] += vv;
        __syncthreads();
    }
    int off = tile_sums[blockIdx.x] + sd[t] - own;
#pragma unroll
    for (int i = 0; i < 4; ++i) {
        int idx = base + t * 4 + i;
        if (idx < n) {
            row_ptr[idx] = off;
            cursor[idx]  = off;
            inv_deg[idx] = 1.0f / (float)max(loc[i], 1);
            off += loc[i];
        }
    }
    if (blockIdx.x == 0 && t == 0) row_ptr[n] = E;
}

__global__ __launch_bounds__(256) void fill_csr(const int* __restrict__ ei,
                                                int* __restrict__ cursor,
                                                int* __restrict__ csr_src, int E, int n) {
    const int range = blockIdx.x & (NPART - 1);
    const int slice = blockIdx.x >> 3;
    const int nr = (n + NPART - 1) / NPART;
    const int lo = range * nr;
    const int hi = min(n, lo + nr);
    const int e1 = min(E, (slice + 1) * SLICE_E);
    for (int e = slice * SLICE_E + threadIdx.x; e < e1; e += 256) {
        int d = ei[(size_t)E + e];
        if (d >= lo && d < hi) {
            int s = ei[e];
            if ((unsigned)s < (unsigned)n) {
                int pos = atomicAdd(&cursor[d], 1);
                csr_src[pos] = s;
            }
        }
    }
}

// ---------------------------------------------------------------- converts
__global__ __launch_bounds__(256) void cvt_x(const float* __restrict__ in,
                                             u16* __restrict__ outb, int n4) {
    int i = blockIdx.x * 256 + threadIdx.x;
    if (i >= n4) return;
    float4 v = ((const float4*)in)[i];
    ushort4 o;
    o.x = f2bf(v.x); o.y = f2bf(v.y); o.z = f2bf(v.z); o.w = f2bf(v.w);
    ((ushort4*)outb)[i] = o;
}

// Wb1 = cat(w1l,w1r) [256][128] bf16 ; Wb2 = cat(w2l,w2r) [128][128] bf16
__global__ __launch_bounds__(256) void cvt_w(const float* __restrict__ w1l,
                                             const float* __restrict__ w1r,
                                             const float* __restrict__ w2l,
                                             const float* __restrict__ w2r,
                                             u16* __restrict__ Wb1,
                                             u16* __restrict__ Wb2) {
    int i = blockIdx.x * 256 + threadIdx.x;
    if (i < 32768) {
        float v = (i < 16384) ? w1l[i] : w1r[i - 16384];
        Wb1[i] = f2bf(v);
    } else if (i < 49152) {
        int j = i - 32768;
        float v = (j < 8192) ? w2l[j] : w2r[j - 8192];
        Wb2[j] = f2bf(v);
    }
}

// ---------------------------------------------------------------- MFMA dual GEMM
// [outA | outB](bf16) = xb(bf16) @ Wb(bf16).T ; outB += bias.
// Wb is [2*COLS][K] row-major bf16. Block = 4 waves; wave w: rows
// blk*128 + w*32 .. +32 (two 16-row MFMA tiles), all 2*COLS cols.
// Frag facts (m89/m120): A[m=lane&15][k=quad*8+j], B[k=quad*8+j][n=lane&15],
// D: col=lane&15, row=quad*4+reg. Both frags = 8 contiguous k's of a row.
template <int K, int COLS>
__global__ __launch_bounds__(256) void gemm_mfma(const u16* __restrict__ xb,
                                                 const u16* __restrict__ Wb,
                                                 const float* __restrict__ bias,
                                                 u16* __restrict__ outA,
                                                 u16* __restrict__ outB,
                                                 int nrows) {
    constexpr int NCOL = 2 * COLS;
    constexpr int NCT  = NCOL / 16;          // 16-col tiles
    constexpr int KS   = K / 32;             // k-steps
    constexpr int WROW = K + 8;              // padded row (272B @K=128): conflict-free b128
    __shared__ u16 wl[NCOL * WROW];

    const int t = threadIdx.x;
    // stage all weights into LDS (uint4 = 8 bf16 per copy)
    for (int i = t; i < NCOL * (K / 8); i += 256) {
        int r = i / (K / 8), p = i % (K / 8);
        *(uint4*)&wl[r * WROW + p * 8] = *(const uint4*)&Wb[(size_t)r * K + p * 8];
    }
    __syncthreads();

    const int wv    = t >> 6;
    const int lane  = t & 63;
    const int cl    = lane & 15;
    const int quad  = lane >> 4;
    const int rbase = blockIdx.x * 128 + wv * 32;

    // A fragments for 2 row-tiles, all k-steps (held in VGPRs)
    bf16x8 afrag[2][KS];
#pragma unroll
    for (int tile = 0; tile < 2; ++tile) {
        int r = rbase + tile * 16 + cl;
        const u16* src = xb + (size_t)min(r, nrows - 1) * K + quad * 8;
#pragma unroll
        for (int ks = 0; ks < KS; ++ks)
            afrag[tile][ks] = *(const bf16x8*)(src + ks * 32);
    }

#pragma unroll
    for (int ct = 0; ct < NCT; ++ct) {
        f32x4 acc0 = {0.f, 0.f, 0.f, 0.f};
        f32x4 acc1 = {0.f, 0.f, 0.f, 0.f};
        const u16* wp = &wl[(ct * 16 + cl) * WROW + quad * 8];
#pragma unroll
        for (int ks = 0; ks < KS; ++ks) {
            bf16x8 bfrag = *(const bf16x8*)(wp + ks * 32);
            acc0 = __builtin_amdgcn_mfma_f32_16x16x32_bf16(afrag[0][ks], bfrag, acc0, 0, 0, 0);
            acc1 = __builtin_amdgcn_mfma_f32_16x16x32_bf16(afrag[1][ks], bfrag, acc1, 0, 0, 0);
        }
        int gc = ct * 16 + cl;
        bool isA = gc < COLS;
        float bv = bias[isA ? 0 : gc - COLS];
        if (isA) bv = 0.f;
        u16* dst = isA ? (outA + gc) : (outB + (gc - COLS));
#pragma unroll
        for (int tile = 0; tile < 2; ++tile) {
            f32x4 a = tile ? acc1 : acc0;
#pragma unroll
            for (int r = 0; r < 4; ++r) {
                int row = rbase + tile * 16 + quad * 4 + r;
                if (row < nrows) dst[(size_t)row * COLS] = f2bf(a[r] + bv);
            }
        }
    }
}

// ---------------------------------------------------------------- aggregate + combine
// out[n] = relu?( (sum_{s in csr[n]} gl[s]) * inv_deg[n] + other[n] )
// gl, other: bf16 [n][C]. out: bf16 (OUTBF) or fp32. Lane covers 8 cols.
template <int C, bool OUTBF>
__global__ __launch_bounds__(256) void agg_bf(const u16* __restrict__ gl,
                                              const u16* __restrict__ other,
                                              const int* __restrict__ row_ptr,
                                              const int* __restrict__ csr_src,
                                              const float* __restrict__ inv_deg,
                                              void* __restrict__ outp,
                                              int n, int do_relu) {
    constexpr int G = C / 8;                 // lanes per node
    int t = threadIdx.x;
    int node = blockIdx.x * (256 / G) + t / G;
    int l = t % G;
    if (node >= n) return;

    int p0 = row_ptr[node], p1 = row_ptr[node + 1];
    float a[8] = {0.f, 0.f, 0.f, 0.f, 0.f, 0.f, 0.f, 0.f};
    const size_t coff = (size_t)l * 8;
    for (int p = p0; p < p1; ++p) {
        int s = csr_src[p];
        uint4 v = *(const uint4*)(gl + (size_t)s * C + coff);
        a[0] += bflo(v.x); a[1] += bfhi(v.x);
        a[2] += bflo(v.y); a[3] += bfhi(v.y);
        a[4] += bflo(v.z); a[5] += bfhi(v.z);
        a[6] += bflo(v.w); a[7] += bfhi(v.w);
    }
    float id = inv_deg[node];
    uint4 o = *(const uint4*)(other + (size_t)node * C + coff);
    float r[8];
    r[0] = fmaf(a[0], id, bflo(o.x)); r[1] = fmaf(a[1], id, bfhi(o.x));
    r[2] = fmaf(a[2], id, bflo(o.y)); r[3] = fmaf(a[3], id, bfhi(o.y));
    r[4] = fmaf(a[4], id, bflo(o.z)); r[5] = fmaf(a[5], id, bfhi(o.z));
    r[6] = fmaf(a[6], id, bflo(o.w)); r[7] = fmaf(a[7], id, bfhi(o.w));
    if (do_relu) {
#pragma unroll
        for (int j = 0; j < 8; ++j) r[j] = fmaxf(r[j], 0.f);
    }
    if (OUTBF) {
        uint4 w;
        w.x = (unsigned)f2bf(r[0]) | ((unsigned)f2bf(r[1]) << 16);
        w.y = (unsigned)f2bf(r[2]) | ((unsigned)f2bf(r[3]) << 16);
        w.z = (unsigned)f2bf(r[4]) | ((unsigned)f2bf(r[5]) << 16);
        w.w = (unsigned)f2bf(r[6]) | ((unsigned)f2bf(r[7]) << 16);
        *(uint4*)((u16*)outp + (size_t)node * C + coff) = w;
    } else {
        float* po = (float*)outp + (size_t)node * C + coff;
        ((float4*)po)[0] = make_float4(r[0], r[1], r[2], r[3]);
        ((float4*)po)[1] = make_float4(r[4], r[5], r[6], r[7]);
    }
}

// ---------------------------------------------------------------- decode
__global__ __launch_bounds__(256) void decode(const float* __restrict__ z,
                                              const int* __restrict__ ei,
                                              float* __restrict__ out, int E, int n) {
    int t = blockIdx.x * 256 + threadIdx.x;
    int e = t >> 4, l = t & 15;
    if (e >= E) return;
    int s = ei[e];
    int d = ei[(size_t)E + e];
    float p = 0.f;
    if ((unsigned)s < (unsigned)n && (unsigned)d < (unsigned)n) {
        float4 a = ((const float4*)(z + (size_t)s * OUT_C))[l];
        float4 b = ((const float4*)(z + (size_t)d * OUT_C))[l];
        p = a.x * b.x + a.y * b.y + a.z * b.z + a.w * b.w;
    }
    p += __shfl_xor(p, 8);
    p += __shfl_xor(p, 4);
    p += __shfl_xor(p, 2);
    p += __shfl_xor(p, 1);
    if (l == 0) out[e] = p;
}

// ---------------------------------------------------------------- launch
extern "C" void kernel_launch(void* const* d_in, const int* in_sizes, int n_in,
                              void* d_out, int out_size, void* d_ws, size_t ws_size,
                              hipStream_t stream) {
    const float* x   = (const float*)d_in[0];
    const int*   ei  = (const int*)d_in[1];
    const float* w1l = (const float*)d_in[2];
    const float* w1r = (const float*)d_in[3];
    const float* b1  = (const float*)d_in[4];
    const float* w2l = (const float*)d_in[5];
    const float* w2r = (const float*)d_in[6];
    const float* b2  = (const float*)d_in[7];
    float*       out = (float*)d_out;

    const int N = in_sizes[0] / IN_C;
    const int E = in_sizes[1] / 2;

    auto alignup = [](size_t v) { return (v + 255) & ~(size_t)255; };
    char* p = (char*)d_ws;
    int*   cnt       = (int*)p;   p += alignup((size_t)N * 4);
    int*   row_ptr   = (int*)p;   p += alignup((size_t)(N + 1) * 4);
    int*   cursor    = (int*)p;   p += alignup((size_t)N * 4);
    int*   tile_sums = (int*)p;   p += alignup((size_t)256 * 4);
    float* inv_deg   = (float*)p; p += alignup((size_t)N * 4);
    int*   csr_src   = (int*)p;   p += alignup((size_t)E * 4);
    u16*   Wb1       = (u16*)p;   p += alignup((size_t)2 * HID_C * IN_C * 2);
    u16*   Wb2       = (u16*)p;   p += alignup((size_t)2 * OUT_C * HID_C * 2);
    u16*   xb        = (u16*)p;   p += alignup((size_t)N * IN_C * 2);    // -> z (fp32 N*64)
    u16*   xlb       = (u16*)p;   p += alignup((size_t)N * HID_C * 2);   // -> hlb
    u16*   xrb       = (u16*)p;   p += alignup((size_t)N * HID_C * 2);   // -> hrb
    u16*   hb        = (u16*)p;   p += alignup((size_t)N * HID_C * 2);

    u16*   hlb = xlb;                       // reuse (xl dead after agg1)
    u16*   hrb = xrb;
    float* z   = (float*)xb;                // reuse (xb dead after gemm1); N*64 fp32

    const int nt = (N + 1023) / 1024;
    const int nslice = (E + SLICE_E - 1) / SLICE_E;

    // converts (independent of CSR)
    cvt_x<<<(N * IN_C / 4 + 255) / 256, 256, 0, stream>>>(x, xb, N * IN_C / 4);
    cvt_w<<<192, 256, 0, stream>>>(w1l, w1r, w2l, w2r, Wb1, Wb2);

    // CSR build (count/fill XCD-partitioned by dst range)
    hipMemsetAsync(cnt, 0, (size_t)N * 4, stream);
    count_deg<<<nslice * NPART, 256, 0, stream>>>(ei, cnt, E, N);
    scan_partial<<<nt, 256, 0, stream>>>(cnt, tile_sums, N);
    scan_tiles<<<1, 256, 0, stream>>>(tile_sums, nt);
    scan_final<<<nt, 256, 0, stream>>>(cnt, tile_sums, row_ptr, cursor, inv_deg, N, E);
    fill_csr<<<nslice * NPART, 256, 0, stream>>>(ei, cursor, csr_src, E, N);

    const int rb = (N + 127) / 128;

    // Layer 1: xl = x@w1l.T ; xr = x@w1r.T + b1   (both bf16)
    gemm_mfma<IN_C, HID_C><<<rb, 256, 0, stream>>>(xb, Wb1, b1, xlb, xrb, N);
    // h = relu(agg(xl)/deg + xr) -> bf16
    agg_bf<HID_C, true><<<(N + 15) / 16, 256, 0, stream>>>(xlb, xrb, row_ptr, csr_src,
                                                           inv_deg, hb, N, 1);

    // Layer 2: hl = h@w2l.T ; hr = h@w2r.T + b2   (both bf16)
    gemm_mfma<HID_C, OUT_C><<<rb, 256, 0, stream>>>(hb, Wb2, b2, hlb, hrb, N);
    // z = agg(hl)/deg + hr -> fp32
    agg_bf<OUT_C, false><<<(N + 31) / 32, 256, 0, stream>>>(hlb, hrb, row_ptr, csr_src,
                                                            inv_deg, z, N, 0);

    // decode
    decode<<<((size_t)E * 16 + 255) / 256, 256, 0, stream>>>(z, ei, out, E, N);
}

// Round 6
// 468.433 us; speedup vs baseline: 2.0977x; 1.1205x over previous
//
#include <hip/hip_runtime.h>

// GraphSAGE link predictor, bf16-MFMA edition.
//   h = relu( mean_agg(x)@w1l.T + b1 + x@w1r.T )
//   z = mean_agg(h)@w2l.T + b2 + h@w2r.T
//   out[e] = dot(z[src[e]], z[dst[e]])
//
// R4: XCD-partitioned CSR build. R5: bf16 MFMA GEMMs (gemm 134->~15us).
// R6: R5 counters: decode 100us, FETCH 351MB @3.7TB/s = HBM-random-gather
//     bound on fp32 z (256B rows over 25.6MB array). (a) z stored bf16:
//     halves gather rows + array fits caches better. (b) layer-1 uses
//     agg-then-project: agg(x)@w1l.T == agg(x@w1l.T), so aggregate xb
//     directly and fuse layer 1 into ONE GEMM h=relu([ag1|x]@[w1l|w1r].T+b1)
//     (K=256) — deletes xl/xr intermediates (~75MB traffic) and takes gemm1
//     off agg1's critical path. Layer 2 keeps project-then-agg (64-wide gather).
//
// edge_index arrives as int32 (harness converts int64 inputs).

#define IN_C      128
#define HID_C     128
#define OUT_C     64
#define NPART     8
#define SLICE_E   4096

typedef unsigned short u16;
typedef __attribute__((ext_vector_type(8))) __bf16 bf16x8;
typedef __attribute__((ext_vector_type(4))) float f32x4;

__device__ inline u16 f2bf(float f) {                 // RNE f32 -> bf16
    unsigned u = __float_as_uint(f);
    u += 0x7fff + ((u >> 16) & 1);
    return (u16)(u >> 16);
}
__device__ inline float bflo(unsigned v) { return __uint_as_float(v << 16); }
__device__ inline float bfhi(unsigned v) { return __uint_as_float(v & 0xffff0000u); }

// ---------------------------------------------------------------- CSR build
__global__ __launch_bounds__(256) void count_deg(const int* __restrict__ ei,
                                                 int* __restrict__ cnt, int E, int n) {
    const int range = blockIdx.x & (NPART - 1);
    const int slice = blockIdx.x >> 3;
    const int nr = (n + NPART - 1) / NPART;
    const int lo = range * nr;
    const int hi = min(n, lo + nr);
    const int e1 = min(E, (slice + 1) * SLICE_E);
    for (int e = slice * SLICE_E + threadIdx.x; e < e1; e += 256) {
        int d = ei[(size_t)E + e];
        if (d >= lo && d < hi) atomicAdd(&cnt[d], 1);
    }
}

__global__ __launch_bounds__(256) void scan_partial(const int* __restrict__ cnt,
                                                    int* __restrict__ tile_sums, int n) {
    __shared__ int sd[256];
    int t = threadIdx.x;
    int base = blockIdx.x * 1024;
    int s = 0;
#pragma unroll
    for (int i = 0; i < 4; ++i) {
        int idx = base + t * 4 + i;
        if (idx < n) s += cnt[idx];
    }
    sd[t] = s;
    __syncthreads();
    for (int o = 128; o > 0; o >>= 1) {
        if (t < o) sd[t] += sd[t + o];
        __syncthreads();
    }
    if (t == 0) tile_sums[blockIdx.x] = sd[0];
}

__global__ __launch_bounds__(256) void scan_tiles(int* __restrict__ tile_sums, int nt) {
    __shared__ int sd[256];
    int t = threadIdx.x;
    int v = (t < nt) ? tile_sums[t] : 0;
    sd[t] = v;
    __syncthreads();
    for (int o = 1; o < 256; o <<= 1) {
        int vv = 0;
        if (t >= o) vv = sd[t - o];
        __syncthreads();
        sd[t] += vv;
        __syncthreads();
    }
    if (t < nt) tile_sums[t] = sd[t] - v;   // exclusive
}

__global__ __launch_bounds__(256) void scan_final(const int* __restrict__ cnt,
                                                  const int* __restrict__ tile_sums,
                                                  int* __restrict__ row_ptr,
                                                  int* __restrict__ cursor,
                                                  float* __restrict__ inv_deg,
                                                  int n, int E) {
    __shared__ int sd[256];
    int t = threadIdx.x;
    int base = blockIdx.x * 1024;
    int loc[4];
    int s = 0;
#pragma unroll
    for (int i = 0; i < 4; ++i) {
        int idx = base + t * 4 + i;
        loc[i] = (idx < n) ? cnt[idx] : 0;
        s += loc[i];
    }
    int own = s;
    sd[t] = s;
    __syncthreads();
    for (int o = 1; o < 256; o <<= 1) {
        int vv = 0;
        if (t >= o) vv = sd[t - o];
        __syncthreads();
        sd[t] += vv;
        __syncthreads();
    }
    int off = tile_sums[blockIdx.x] + sd[t] - own;
#pragma unroll
    for (int i = 0; i < 4; ++i) {
        int idx = base + t * 4 + i;
        if (idx < n) {
            row_ptr[idx] = off;
            cursor[idx]  = off;
            inv_deg[idx] = 1.0f / (float)max(loc[i], 1);
            off += loc[i];
        }
    }
    if (blockIdx.x == 0 && t == 0) row_ptr[n] = E;
}

__global__ __launch_bounds__(256) void fill_csr(const int* __restrict__ ei,
                                                int* __restrict__ cursor,
                                                int* __restrict__ csr_src, int E, int n) {
    const int range = blockIdx.x & (NPART - 1);
    const int slice = blockIdx.x >> 3;
    const int nr = (n + NPART - 1) / NPART;
    const int lo = range * nr;
    const int hi = min(n, lo + nr);
    const int e1 = min(E, (slice + 1) * SLICE_E);
    for (int e = slice * SLICE_E + threadIdx.x; e < e1; e += 256) {
        int d = ei[(size_t)E + e];
        if (d >= lo && d < hi) {
            int s = ei[e];
            if ((unsigned)s < (unsigned)n) {
                int pos = atomicAdd(&cursor[d], 1);
                csr_src[pos] = s;
            }
        }
    }
}

// ---------------------------------------------------------------- converts
__global__ __launch_bounds__(256) void cvt_x(const float* __restrict__ in,
                                             u16* __restrict__ outb, int n4) {
    int i = blockIdx.x * 256 + threadIdx.x;
    if (i >= n4) return;
    float4 v = ((const float4*)in)[i];
    ushort4 o;
    o.x = f2bf(v.x); o.y = f2bf(v.y); o.z = f2bf(v.z); o.w = f2bf(v.w);
    ((ushort4*)outb)[i] = o;
}

// Wb1[c][0:128]=w1l[c], Wb1[c][128:256]=w1r[c]  -> [128][256] bf16
// Wb2 = cat(w2l,w2r)                             -> [128][128] bf16
__global__ __launch_bounds__(256) void cvt_w(const float* __restrict__ w1l,
                                             const float* __restrict__ w1r,
                                             const float* __restrict__ w2l,
                                             const float* __restrict__ w2r,
                                             u16* __restrict__ Wb1,
                                             u16* __restrict__ Wb2) {
    int i = blockIdx.x * 256 + threadIdx.x;
    if (i < 32768) {
        int c = i >> 8, k = i & 255;
        float v = (k < 128) ? w1l[c * 128 + k] : w1r[c * 128 + (k - 128)];
        Wb1[i] = f2bf(v);
    } else if (i < 49152) {
        int j = i - 32768;
        float v = (j < 8192) ? w2l[j] : w2r[j - 8192];
        Wb2[j] = f2bf(v);
    }
}

// ---------------------------------------------------------------- fused layer-1 GEMM
// h = relu([A0|A1] @ W.T + b), A0/A1 [n][128] bf16, W [128][256] bf16 -> h [n][128] bf16
// Frag facts (m89/m120): A[m=lane&15][k=quad*8+j], B[k=quad*8+j][n=lane&15],
// D: col=lane&15, row=quad*4+reg. Both frags = 8 contiguous k's of a row.
__global__ __launch_bounds__(256) void gemm_l1(const u16* __restrict__ A0,
                                               const u16* __restrict__ A1,
                                               const u16* __restrict__ Wb,
                                               const float* __restrict__ bias,
                                               u16* __restrict__ outp, int nrows) {
    constexpr int K    = 256;
    constexpr int COLS = 128;
    constexpr int KS   = K / 32;             // 8
    constexpr int NCT  = COLS / 16;          // 8
    constexpr int WROW = K + 8;
    __shared__ u16 wl[COLS * WROW];          // 67.6 KB

    const int t = threadIdx.x;
    for (int i = t; i < COLS * (K / 8); i += 256) {
        int r = i >> 5, p = i & 31;
        *(uint4*)&wl[r * WROW + p * 8] = *(const uint4*)&Wb[(size_t)r * K + p * 8];
    }
    __syncthreads();

    const int wv    = t >> 6;
    const int lane  = t & 63;
    const int cl    = lane & 15;
    const int quad  = lane >> 4;
    const int rbase = blockIdx.x * 128 + wv * 32;

    bf16x8 afrag[2][KS];
#pragma unroll
    for (int tile = 0; tile < 2; ++tile) {
        int r = min(rbase + tile * 16 + cl, nrows - 1);
        const u16* s0 = A0 + (size_t)r * 128 + quad * 8;
        const u16* s1 = A1 + (size_t)r * 128 + quad * 8;
#pragma unroll
        for (int ks = 0; ks < 4; ++ks) {
            afrag[tile][ks]     = *(const bf16x8*)(s0 + ks * 32);
            afrag[tile][4 + ks] = *(const bf16x8*)(s1 + ks * 32);
        }
    }

#pragma unroll
    for (int ct = 0; ct < NCT; ++ct) {
        f32x4 acc0 = {0.f, 0.f, 0.f, 0.f};
        f32x4 acc1 = {0.f, 0.f, 0.f, 0.f};
        const u16* wp = &wl[(ct * 16 + cl) * WROW + quad * 8];
#pragma unroll
        for (int ks = 0; ks < KS; ++ks) {
            bf16x8 bfrag = *(const bf16x8*)(wp + ks * 32);
            acc0 = __builtin_amdgcn_mfma_f32_16x16x32_bf16(afrag[0][ks], bfrag, acc0, 0, 0, 0);
            acc1 = __builtin_amdgcn_mfma_f32_16x16x32_bf16(afrag[1][ks], bfrag, acc1, 0, 0, 0);
        }
        int gc = ct * 16 + cl;
        float bv = bias[gc];
#pragma unroll
        for (int tile = 0; tile < 2; ++tile) {
            f32x4 a = tile ? acc1 : acc0;
#pragma unroll
            for (int r = 0; r < 4; ++r) {
                int row = rbase + tile * 16 + quad * 4 + r;
                if (row < nrows)
                    outp[(size_t)row * COLS + gc] = f2bf(fmaxf(a[r] + bv, 0.f));
            }
        }
    }
}

// ---------------------------------------------------------------- dual GEMM (layer 2)
// [outA | outB](bf16) = xb @ Wb.T ; outB += bias. Wb [2*COLS][K] bf16.
template <int K, int COLS>
__global__ __launch_bounds__(256) void gemm_mfma(const u16* __restrict__ xb,
                                                 const u16* __restrict__ Wb,
                                                 const float* __restrict__ bias,
                                                 u16* __restrict__ outA,
                                                 u16* __restrict__ outB,
                                                 int nrows) {
    constexpr int NCOL = 2 * COLS;
    constexpr int NCT  = NCOL / 16;
    constexpr int KS   = K / 32;
    constexpr int WROW = K + 8;
    __shared__ u16 wl[NCOL * WROW];

    const int t = threadIdx.x;
    for (int i = t; i < NCOL * (K / 8); i += 256) {
        int r = i / (K / 8), p = i % (K / 8);
        *(uint4*)&wl[r * WROW + p * 8] = *(const uint4*)&Wb[(size_t)r * K + p * 8];
    }
    __syncthreads();

    const int wv    = t >> 6;
    const int lane  = t & 63;
    const int cl    = lane & 15;
    const int quad  = lane >> 4;
    const int rbase = blockIdx.x * 128 + wv * 32;

    bf16x8 afrag[2][KS];
#pragma unroll
    for (int tile = 0; tile < 2; ++tile) {
        int r = rbase + tile * 16 + cl;
        const u16* src = xb + (size_t)min(r, nrows - 1) * K + quad * 8;
#pragma unroll
        for (int ks = 0; ks < KS; ++ks)
            afrag[tile][ks] = *(const bf16x8*)(src + ks * 32);
    }

#pragma unroll
    for (int ct = 0; ct < NCT; ++ct) {
        f32x4 acc0 = {0.f, 0.f, 0.f, 0.f};
        f32x4 acc1 = {0.f, 0.f, 0.f, 0.f};
        const u16* wp = &wl[(ct * 16 + cl) * WROW + quad * 8];
#pragma unroll
        for (int ks = 0; ks < KS; ++ks) {
            bf16x8 bfrag = *(const bf16x8*)(wp + ks * 32);
            acc0 = __builtin_amdgcn_mfma_f32_16x16x32_bf16(afrag[0][ks], bfrag, acc0, 0, 0, 0);
            acc1 = __builtin_amdgcn_mfma_f32_16x16x32_bf16(afrag[1][ks], bfrag, acc1, 0, 0, 0);
        }
        int gc = ct * 16 + cl;
        bool isA = gc < COLS;
        float bv = isA ? 0.f : bias[gc - COLS];
        u16* dst = isA ? (outA + gc) : (outB + (gc - COLS));
#pragma unroll
        for (int tile = 0; tile < 2; ++tile) {
            f32x4 a = tile ? acc1 : acc0;
#pragma unroll
            for (int r = 0; r < 4; ++r) {
                int row = rbase + tile * 16 + quad * 4 + r;
                if (row < nrows) dst[(size_t)row * COLS] = f2bf(a[r] + bv);
            }
        }
    }
}

// ---------------------------------------------------------------- aggregate
// out[n] = (sum_{s in csr[n]} gl[s]) * inv_deg[n]  [+ other[n]] ; bf16 in/out.
template <int C, bool HAS_OTHER>
__global__ __launch_bounds__(256) void agg_bf(const u16* __restrict__ gl,
                                              const u16* __restrict__ other,
                                              const int* __restrict__ row_ptr,
                                              const int* __restrict__ csr_src,
                                              const float* __restrict__ inv_deg,
                                              u16* __restrict__ outp, int n) {
    constexpr int G = C / 8;                 // lanes per node
    int t = threadIdx.x;
    int node = blockIdx.x * (256 / G) + t / G;
    int l = t % G;
    if (node >= n) return;

    int p0 = row_ptr[node], p1 = row_ptr[node + 1];
    float a[8] = {0.f, 0.f, 0.f, 0.f, 0.f, 0.f, 0.f, 0.f};
    const size_t coff = (size_t)l * 8;
    for (int p = p0; p < p1; ++p) {
        int s = csr_src[p];
        uint4 v = *(const uint4*)(gl + (size_t)s * C + coff);
        a[0] += bflo(v.x); a[1] += bfhi(v.x);
        a[2] += bflo(v.y); a[3] += bfhi(v.y);
        a[4] += bflo(v.z); a[5] += bfhi(v.z);
        a[6] += bflo(v.w); a[7] += bfhi(v.w);
    }
    float id = inv_deg[node];
    float r[8];
    if (HAS_OTHER) {
        uint4 o = *(const uint4*)(other + (size_t)node * C + coff);
        r[0] = fmaf(a[0], id, bflo(o.x)); r[1] = fmaf(a[1], id, bfhi(o.x));
        r[2] = fmaf(a[2], id, bflo(o.y)); r[3] = fmaf(a[3], id, bfhi(o.y));
        r[4] = fmaf(a[4], id, bflo(o.z)); r[5] = fmaf(a[5], id, bfhi(o.z));
        r[6] = fmaf(a[6], id, bflo(o.w)); r[7] = fmaf(a[7], id, bfhi(o.w));
    } else {
#pragma unroll
        for (int j = 0; j < 8; ++j) r[j] = a[j] * id;
    }
    uint4 w;
    w.x = (unsigned)f2bf(r[0]) | ((unsigned)f2bf(r[1]) << 16);
    w.y = (unsigned)f2bf(r[2]) | ((unsigned)f2bf(r[3]) << 16);
    w.z = (unsigned)f2bf(r[4]) | ((unsigned)f2bf(r[5]) << 16);
    w.w = (unsigned)f2bf(r[6]) | ((unsigned)f2bf(r[7]) << 16);
    *(uint4*)(outp + (size_t)node * C + coff) = w;
}

// ---------------------------------------------------------------- decode (bf16 z)
__global__ __launch_bounds__(256) void decode(const u16* __restrict__ z,
                                              const int* __restrict__ ei,
                                              float* __restrict__ out, int E, int n) {
    int t = blockIdx.x * 256 + threadIdx.x;
    int e = t >> 3, l = t & 7;
    if (e >= E) return;
    int s = ei[e];
    int d = ei[(size_t)E + e];
    float p = 0.f;
    if ((unsigned)s < (unsigned)n && (unsigned)d < (unsigned)n) {
        uint4 a = *(const uint4*)(z + (size_t)s * OUT_C + l * 8);
        uint4 b = *(const uint4*)(z + (size_t)d * OUT_C + l * 8);
        p  = bflo(a.x) * bflo(b.x) + bfhi(a.x) * bfhi(b.x);
        p += bflo(a.y) * bflo(b.y) + bfhi(a.y) * bfhi(b.y);
        p += bflo(a.z) * bflo(b.z) + bfhi(a.z) * bfhi(b.z);
        p += bflo(a.w) * bflo(b.w) + bfhi(a.w) * bfhi(b.w);
    }
    p += __shfl_xor(p, 4);
    p += __shfl_xor(p, 2);
    p += __shfl_xor(p, 1);
    if (l == 0) out[e] = p;
}

// ---------------------------------------------------------------- launch
extern "C" void kernel_launch(void* const* d_in, const int* in_sizes, int n_in,
                              void* d_out, int out_size, void* d_ws, size_t ws_size,
                              hipStream_t stream) {
    const float* x   = (const float*)d_in[0];
    const int*   ei  = (const int*)d_in[1];
    const float* w1l = (const float*)d_in[2];
    const float* w1r = (const float*)d_in[3];
    const float* b1  = (const float*)d_in[4];
    const float* w2l = (const float*)d_in[5];
    const float* w2r = (const float*)d_in[6];
    const float* b2  = (const float*)d_in[7];
    float*       out = (float*)d_out;

    const int N = in_sizes[0] / IN_C;
    const int E = in_sizes[1] / 2;

    auto alignup = [](size_t v) { return (v + 255) & ~(size_t)255; };
    char* p = (char*)d_ws;
    int*   cnt       = (int*)p;   p += alignup((size_t)N * 4);
    int*   row_ptr   = (int*)p;   p += alignup((size_t)(N + 1) * 4);
    int*   cursor    = (int*)p;   p += alignup((size_t)N * 4);
    int*   tile_sums = (int*)p;   p += alignup((size_t)256 * 4);
    float* inv_deg   = (float*)p; p += alignup((size_t)N * 4);
    int*   csr_src   = (int*)p;   p += alignup((size_t)E * 4);
    u16*   Wb1       = (u16*)p;   p += alignup((size_t)HID_C * 2 * IN_C * 2);
    u16*   Wb2       = (u16*)p;   p += alignup((size_t)2 * OUT_C * HID_C * 2);
    u16*   xb        = (u16*)p;   p += alignup((size_t)N * IN_C * 2);
    u16*   ag1       = (u16*)p;   p += alignup((size_t)N * HID_C * 2);
    u16*   hb        = (u16*)p;   p += alignup((size_t)N * HID_C * 2);
    u16*   hlb       = (u16*)p;   p += alignup((size_t)N * OUT_C * 2);
    u16*   hrb       = (u16*)p;   p += alignup((size_t)N * OUT_C * 2);
    u16*   zb        = (u16*)p;   p += alignup((size_t)N * OUT_C * 2);

    const int nt = (N + 1023) / 1024;
    const int nslice = (E + SLICE_E - 1) / SLICE_E;

    // converts (independent of CSR)
    cvt_x<<<(N * IN_C / 4 + 255) / 256, 256, 0, stream>>>(x, xb, N * IN_C / 4);
    cvt_w<<<192, 256, 0, stream>>>(w1l, w1r, w2l, w2r, Wb1, Wb2);

    // CSR build (count/fill XCD-partitioned by dst range)
    hipMemsetAsync(cnt, 0, (size_t)N * 4, stream);
    count_deg<<<nslice * NPART, 256, 0, stream>>>(ei, cnt, E, N);
    scan_partial<<<nt, 256, 0, stream>>>(cnt, tile_sums, N);
    scan_tiles<<<1, 256, 0, stream>>>(tile_sums, nt);
    scan_final<<<nt, 256, 0, stream>>>(cnt, tile_sums, row_ptr, cursor, inv_deg, N, E);
    fill_csr<<<nslice * NPART, 256, 0, stream>>>(ei, cursor, csr_src, E, N);

    const int rb = (N + 127) / 128;

    // ag1 = mean_agg(xb)
    agg_bf<HID_C, false><<<(N + 15) / 16, 256, 0, stream>>>(xb, nullptr, row_ptr,
                                                            csr_src, inv_deg, ag1, N);
    // h = relu([ag1|xb] @ [w1l|w1r].T + b1)
    gemm_l1<<<rb, 256, 0, stream>>>(ag1, xb, Wb1, b1, hb, N);

    // hl = h@w2l.T ; hr = h@w2r.T + b2
    gemm_mfma<HID_C, OUT_C><<<rb, 256, 0, stream>>>(hb, Wb2, b2, hlb, hrb, N);
    // z = agg(hl)/deg + hr  (bf16)
    agg_bf<OUT_C, true><<<(N + 31) / 32, 256, 0, stream>>>(hlb, hrb, row_ptr, csr_src,
                                                           inv_deg, zb, N);

    // decode (bf16 z)
    decode<<<((size_t)E * 8 + 255) / 256, 256, 0, stream>>>(zb, ei, out, E, N);
}